// Round 10
// baseline (187.953 us; speedup 1.0000x reference)
//
#include <hip/hip_runtime.h>
#include <hip/hip_bf16.h>
#include <hip/hip_fp16.h>

#define N_   8
#define T_   300
#define U_   60
#define U1_  61
#define EENC 320
#define NHID 512
#define VOC  128
#define SKROWS 384
#define INV_LN2 1.4426950408889634f
#define LN2 0.6931471805599453f
#define SCALE2 2.8853900817779268f   // 2*log2(e)

typedef __attribute__((ext_vector_type(8))) short bf16x8;
typedef __attribute__((ext_vector_type(4))) float f32x4;

__device__ __forceinline__ unsigned short f2bf(float f) {
    unsigned int u = __float_as_uint(f);
    u += 0x7fff + ((u >> 16) & 1);          // RNE
    return (unsigned short)(u >> 16);
}

// log-add-exp in log2 domain, NaN/inf-proof: fminf returns the non-NaN operand,
// so a rogue inf/NaN operand degrades to max(x,y) instead of NaN.
// QUARANTINE (do not reintroduce without isolated proof): DPP wave_shr (invalid
// on CDNA4, R6), __builtin_amdgcn_logf / __builtin_amdgcn_exp2f inside this
// function (R7/R8 reds), cvt_pk sigma-pack (R8 red), pre-swizzled WoT2s +
// global_load_lds B-staging (R5 red).
__device__ __forceinline__ float lae2(float x, float y) {
    float m = fmaxf(x, y);
    float d = fminf(fabsf(x - y), 1e30f);
    return m + log2f(1.f + exp2f(-d));
}

__device__ __forceinline__ unsigned gload4(const void* p) {
    unsigned v;
    asm volatile("global_load_dword %0, %1, off" : "=v"(v) : "v"(p) : "memory");
    return v;
}

// ---- transpose-convert: WjT[512][320]=bf(Wj^T); WoT2[128][512]=bf(-2*Wo^T); bosum[c]=sum_k Wo[k][c] ----
__global__ __launch_bounds__(256) void convert_w(
    const float* __restrict__ Wj, const float* __restrict__ Wo,
    unsigned short* __restrict__ WjT, unsigned short* __restrict__ WoT2,
    float* __restrict__ bosum)
{
    __shared__ float tile[32][33];
    int bid = blockIdx.x;
    const float* S; unsigned short* D; int k0, c0, K, C; bool isWo;
    if (bid < 160) { S = Wj; D = WjT; K = 320; C = 512; k0 = (bid >> 4) * 32; c0 = (bid & 15) * 32; isWo = false; }
    else { bid -= 160; S = Wo; D = WoT2; K = 512; C = 128; k0 = (bid >> 2) * 32; c0 = (bid & 3) * 32; isWo = true; }
    const int tx = threadIdx.x & 31, ty = threadIdx.x >> 5;
    float part = 0.f;
    #pragma unroll
    for (int i = 0; i < 32; i += 8) {
        float v = S[(k0 + ty + i) * C + c0 + tx];
        tile[ty + i][tx] = v;
        part += v;
    }
    __syncthreads();
    const float mulf = isWo ? -2.f : 1.f;
    #pragma unroll
    for (int i = 0; i < 32; i += 8)
        D[(c0 + ty + i) * K + k0 + tx] = f2bf(mulf * tile[tx][ty + i]);
    if (isWo) atomicAdd(&bosum[c0 + tx], part);
}

// ---- projection GEMM, 64x128 tiles: C[R,512] = exp2((X[R,320] @ Wj + b) * 2log2e) ----
// Stores EXP2 of the scaled preactivation: joint kernel then needs only
// sigma = rcp(fma(E,D,1)) per element (exp2(e+d) = exp2(e)*exp2(d)).
__global__ __launch_bounds__(256) void proj_mfma(
    const float* __restrict__ Xe, const float* __restrict__ Xd,
    const unsigned short* __restrict__ BT,
    const float* __restrict__ bj,
    float* __restrict__ Ce, float* __restrict__ Cd)
{
    __shared__ short lA[64 * 64];
    __shared__ short lB[128 * 64];
    int bid = blockIdx.x;
    const float* X; float* Cp; const float* bias; int R;
    if (bid < 152) { X = Xe; Cp = Ce; bias = nullptr; R = N_ * T_; }
    else { bid -= 152; X = Xd; Cp = Cd; bias = bj; R = N_ * U1_; }
    const int tid = threadIdx.x, lane = tid & 63, wave = tid >> 6;
    const int rb = bid >> 2, cb = bid & 3;
    const int rh = wave & 1, ch = wave >> 1;
    const int sr = tid >> 3, sg = tid & 7;
    const int frow = lane & 15, fg = lane >> 4, quad = lane >> 4;

    f32x4 acc[2][4];
    f32x4 z = {0.f, 0.f, 0.f, 0.f};
    #pragma unroll
    for (int a = 0; a < 2; ++a)
        #pragma unroll
        for (int b = 0; b < 4; ++b) acc[a][b] = z;

    for (int s = 0; s < 5; ++s) {
        __syncthreads();
        #pragma unroll
        for (int p = 0; p < 2; ++p) {
            int row = sr + p * 32;
            int grow = rb * 64 + row; if (grow >= R) grow = R - 1;
            const float* xp = X + grow * EENC + s * 64 + sg * 8;
            float4 x0 = *(const float4*)xp, x1 = *(const float4*)(xp + 4);
            bf16x8 va;
            va[0] = (short)f2bf(x0.x); va[1] = (short)f2bf(x0.y);
            va[2] = (short)f2bf(x0.z); va[3] = (short)f2bf(x0.w);
            va[4] = (short)f2bf(x1.x); va[5] = (short)f2bf(x1.y);
            va[6] = (short)f2bf(x1.z); va[7] = (short)f2bf(x1.w);
            *(bf16x8*)&lA[row * 64 + ((sg ^ (row & 7)) << 3)] = va;
        }
        #pragma unroll
        for (int p = 0; p < 4; ++p) {
            int col = sr + p * 32;
            bf16x8 vb = *(const bf16x8*)(BT + (cb * 128 + col) * EENC + s * 64 + sg * 8);
            *(bf16x8*)&lB[col * 64 + ((sg ^ (col & 7)) << 3)] = vb;
        }
        __syncthreads();
        #pragma unroll
        for (int ks = 0; ks < 2; ++ks) {
            int g = fg + ks * 4;
            bf16x8 af[2], bf[4];
            #pragma unroll
            for (int rt = 0; rt < 2; ++rt) {
                int row = rh * 32 + rt * 16 + frow;
                af[rt] = *(const bf16x8*)&lA[row * 64 + ((g ^ (row & 7)) << 3)];
            }
            #pragma unroll
            for (int c = 0; c < 4; ++c) {
                int col = ch * 64 + c * 16 + frow;
                bf[c] = *(const bf16x8*)&lB[col * 64 + ((g ^ (col & 7)) << 3)];
            }
            #pragma unroll
            for (int rt = 0; rt < 2; ++rt)
                #pragma unroll
                for (int c = 0; c < 4; ++c)
                    acc[rt][c] = __builtin_amdgcn_mfma_f32_16x16x32_bf16(af[rt], bf[c], acc[rt][c], 0, 0, 0);
        }
    }
    #pragma unroll
    for (int rt = 0; rt < 2; ++rt) {
        int grow0 = rb * 64 + rh * 32 + rt * 16 + quad * 4;
        #pragma unroll
        for (int c = 0; c < 4; ++c) {
            int col = cb * 128 + ch * 64 + c * 16 + frow;
            float b = bias ? bias[col] : 0.f;
            #pragma unroll
            for (int r = 0; r < 4; ++r) {
                int gr = grow0 + r;
                if (gr < R)
                    Cp[gr * NHID + col] = __builtin_amdgcn_exp2f((acc[rt][c][r] + b) * SCALE2);
            }
        }
    }
}

// σ-pack helper: 8x sigma = rcp(fma(E,D,1)) -> bf16x8 (trunc-to-nearest) -> swizzled LDS store
__device__ __forceinline__ void sigstore(short* lAp, float4 ee0, float4 ee1,
                                         float4 dd0, float4 dd1, int row, int sg)
{
    float s0 = __builtin_amdgcn_rcpf(__builtin_fmaf(ee0.x, dd0.x, 1.f));
    float s1 = __builtin_amdgcn_rcpf(__builtin_fmaf(ee0.y, dd0.y, 1.f));
    float s2 = __builtin_amdgcn_rcpf(__builtin_fmaf(ee0.z, dd0.z, 1.f));
    float s3 = __builtin_amdgcn_rcpf(__builtin_fmaf(ee0.w, dd0.w, 1.f));
    float s4 = __builtin_amdgcn_rcpf(__builtin_fmaf(ee1.x, dd1.x, 1.f));
    float s5 = __builtin_amdgcn_rcpf(__builtin_fmaf(ee1.y, dd1.y, 1.f));
    float s6 = __builtin_amdgcn_rcpf(__builtin_fmaf(ee1.z, dd1.z, 1.f));
    float s7 = __builtin_amdgcn_rcpf(__builtin_fmaf(ee1.w, dd1.w, 1.f));
    unsigned b0 = __float_as_uint(s0) + 0x8000u, b1 = __float_as_uint(s1) + 0x8000u;
    unsigned b2 = __float_as_uint(s2) + 0x8000u, b3 = __float_as_uint(s3) + 0x8000u;
    unsigned b4 = __float_as_uint(s4) + 0x8000u, b5 = __float_as_uint(s5) + 0x8000u;
    unsigned b6 = __float_as_uint(s6) + 0x8000u, b7 = __float_as_uint(s7) + 0x8000u;
    union { unsigned u4[4]; bf16x8 v; } va;
    va.u4[0] = __builtin_amdgcn_perm(b1, b0, 0x07060302);
    va.u4[1] = __builtin_amdgcn_perm(b3, b2, 0x07060302);
    va.u4[2] = __builtin_amdgcn_perm(b5, b4, 0x07060302);
    va.u4[3] = __builtin_amdgcn_perm(b7, b6, 0x07060302);
    *(bf16x8*)&lAp[row * 64 + ((sg ^ (row & 7)) << 3)] = va.v;
}

// ---- joint v9: as v7 (R9 green) but DOUBLE-BUFFERED lA/lB with ONE barrier per
//      slice: stage buf[s&1] -> prefetch s+1 -> barrier -> MFMA buf[s&1].
//      Race model: stage(s+1) writes the opposite buffer from MFMA(s) readers;
//      stage(s+2) reuses buf[s&1] only after barrier(s+1), which no wave passes
//      before finishing MFMA(s). Math/layout byte-identical to v7. ----
__global__ __launch_bounds__(256, 5) void joint_mfma(
    const float* __restrict__ encp,          // [2400][512], exp2 of scaled enc preact
    const float* __restrict__ decp,          // [488][512], exp2 of scaled dec preact (+bj)
    const unsigned short* __restrict__ WoT2, // [128][512] bf16 = -2*Wo^T
    const float* __restrict__ bo, const float* __restrict__ bosum,
    const int* __restrict__ targets,
    unsigned short* __restrict__ Zs)
{
    __shared__ short lA[2][64 * 64];         // 16 KB
    __shared__ short lB[2][128 * 64];        // 32 KB
    __shared__ float bo_s[VOC];
    __shared__ int   lab_s[U_];

    const int tid = threadIdx.x, lane = tid & 63, wave = tid >> 6;  // wave 0..3
    const int nt = blockIdx.x;
    const int n = nt / T_, t0 = nt - n * T_;
    if (tid < VOC) bo_s[tid] = bo[tid] + bosum[tid];
    else if (tid < VOC + U_) lab_s[tid - VOC] = targets[n * U_ + (tid - VOC)];

    const int frow = lane & 15, quad = lane >> 4;
    const int sg = tid & 7, sr = tid >> 3;   // sr 0..31, k-octet sg

    f32x4 acc[8];
    f32x4 z = {0.f, 0.f, 0.f, 0.f};
    #pragma unroll
    for (int c = 0; c < 8; ++c) acc[c] = z;

    const int ua0 = min(sr, U_);
    const int ua1 = min(sr + 32, U_);
    const float* dbase0 = decp + (size_t)(n * U1_ + ua0) * NHID + sg * 8;
    const float* dbase1 = decp + (size_t)(n * U1_ + ua1) * NHID + sg * 8;
    const float* ebase  = encp + (size_t)nt * NHID + sg * 8;
    const unsigned short* wbase = WoT2 + sg * 8;

    // prefetch registers (slice s data, loaded one iteration ahead)
    float4 e0, e1, d00, d01, d10, d11;
    bf16x8 vb0, vb1, vb2, vb3;
    e0  = *(const float4*)ebase;        e1  = *(const float4*)(ebase + 4);
    d00 = *(const float4*)dbase0;       d01 = *(const float4*)(dbase0 + 4);
    d10 = *(const float4*)dbase1;       d11 = *(const float4*)(dbase1 + 4);
    vb0 = *(const bf16x8*)(wbase + (size_t)(sr +  0) * NHID);
    vb1 = *(const bf16x8*)(wbase + (size_t)(sr + 32) * NHID);
    vb2 = *(const bf16x8*)(wbase + (size_t)(sr + 64) * NHID);
    vb3 = *(const bf16x8*)(wbase + (size_t)(sr + 96) * NHID);

    for (int s = 0; s < 8; ++s) {            // K=512, slices of 64
        const int pb = s & 1;
        short* lAp = lA[pb];
        short* lBp = lB[pb];
        // ---- B staging from regs into buf pb (other waves may still MFMA buf pb^1) ----
        { int col = sr;      *(bf16x8*)&lBp[col * 64 + ((sg ^ (col & 7)) << 3)] = vb0; }
        { int col = sr + 32; *(bf16x8*)&lBp[col * 64 + ((sg ^ (col & 7)) << 3)] = vb1; }
        { int col = sr + 64; *(bf16x8*)&lBp[col * 64 + ((sg ^ (col & 7)) << 3)] = vb2; }
        { int col = sr + 96; *(bf16x8*)&lBp[col * 64 + ((sg ^ (col & 7)) << 3)] = vb3; }
        // ---- A sigma staging: rows sr and sr+32 (enc chunk shared) ----
        sigstore(lAp, e0, e1, d00, d01, sr,      sg);
        sigstore(lAp, e0, e1, d10, d11, sr + 32, sg);
        // ---- issue next-slice loads; land during barrier + MFMA phase ----
        if (s < 7) {
            const int o = (s + 1) * 64;
            e0  = *(const float4*)(ebase + o);      e1  = *(const float4*)(ebase + o + 4);
            d00 = *(const float4*)(dbase0 + o);     d01 = *(const float4*)(dbase0 + o + 4);
            d10 = *(const float4*)(dbase1 + o);     d11 = *(const float4*)(dbase1 + o + 4);
            vb0 = *(const bf16x8*)(wbase + (size_t)(sr +  0) * NHID + o);
            vb1 = *(const bf16x8*)(wbase + (size_t)(sr + 32) * NHID + o);
            vb2 = *(const bf16x8*)(wbase + (size_t)(sr + 64) * NHID + o);
            vb3 = *(const bf16x8*)(wbase + (size_t)(sr + 96) * NHID + o);
        }
        __syncthreads();                     // buf pb complete & visible
        // ---- MFMA: wave covers rows wave*16..+15, all 128 cols ----
        __builtin_amdgcn_s_setprio(1);
        #pragma unroll
        for (int ks = 0; ks < 2; ++ks) {
            const int g = ks * 4 + quad;
            int ar = wave * 16 + frow;
            bf16x8 af = *(const bf16x8*)&lAp[ar * 64 + ((g ^ (ar & 7)) << 3)];
            #pragma unroll
            for (int c = 0; c < 8; ++c) {
                int col = c * 16 + frow;
                const bf16x8 bfr = *(const bf16x8*)&lBp[col * 64 + ((g ^ (col & 7)) << 3)];
                acc[c] = __builtin_amdgcn_mfma_f32_16x16x32_bf16(af, bfr, acc[c], 0, 0, 0);
            }
        }
        __builtin_amdgcn_s_setprio(0);
    }

    // ---- epilogue: bias + wave-local per-row LSE; fp16 skew Z output ----
    #pragma unroll
    for (int c = 0; c < 8; ++c) {
        float b = bo_s[c * 16 + frow];
        #pragma unroll
        for (int r = 0; r < 4; ++r) acc[c][r] += b;
    }
    float mx[4], sm[4];
    #pragma unroll
    for (int r = 0; r < 4; ++r) {
        float m = acc[0][r];
        #pragma unroll
        for (int c = 1; c < 8; ++c) m = fmaxf(m, acc[c][r]);
        mx[r] = m;
    }
    #pragma unroll
    for (int off = 1; off < 16; off <<= 1)
        #pragma unroll
        for (int r = 0; r < 4; ++r) mx[r] = fmaxf(mx[r], __shfl_xor(mx[r], off));
    #pragma unroll
    for (int r = 0; r < 4; ++r) {
        float ss = 0.f;
        #pragma unroll
        for (int c = 0; c < 8; ++c) ss += __expf(acc[c][r] - mx[r]);
        sm[r] = ss;
    }
    #pragma unroll
    for (int off = 1; off < 16; off <<= 1)
        #pragma unroll
        for (int r = 0; r < 4; ++r) sm[r] += __shfl_xor(sm[r], off);

    #pragma unroll
    for (int r = 0; r < 4; ++r) {
        float lse = mx[r] + __logf(sm[r]);
        int urow = wave * 16 + quad * 4 + r;             // 0..63
        size_t rowz = (size_t)(n * SKROWS + t0 + urow + 1) * 64;
        if (urow < U1_ && frow == 0) {
            __half hh = __float2half_rn((acc[0][r] - lse) * INV_LN2);
            Zs[(rowz + urow) * 2] = __half_as_ushort(hh);
        }
        if (urow < U_) {
            int lab = lab_s[urow];
            if (frow == (lab & 15)) {
                int cw = lab >> 4;
                float pick = acc[0][r];
                #pragma unroll
                for (int c = 1; c < 8; ++c) if (c == cw) pick = acc[c][r];
                __half hh = __float2half_rn((pick - lse) * INV_LN2);
                Zs[(rowz + urow + 1) * 2 + 1] = __half_as_ushort(hh);
            }
        }
    }
}

// ---- dp v4: single block, 512 thr; ONE BATCH PER WAVE (8 working waves),
//      one u-value per lane (61 active lanes/wave), 16-deep dword prefetch ring. ----
__global__ __launch_bounds__(512) void dp_kernel(
    const unsigned* __restrict__ Z,
    const int* __restrict__ inputs_len, const int* __restrict__ targets_len,
    float* __restrict__ out)
{
    __shared__ float losses[N_];
    const int tid = threadIdx.x;
    const int n = tid >> 6;                  // wave index = batch index
    const int u = tid & 63;                  // one u per lane; u<61 meaningful
    const bool u_is0 = (u == 0);

    const unsigned len_t = (unsigned)inputs_len[n];
    const int ui = targets_len[n];
    const int ti = (int)len_t - 1;

    // lane's column of batch n: 4 B per (d,u) half2 cell; row pitch 256 B
    const char* Zn = (const char*)(Z + (size_t)n * SKROWS * 64) + u * 4;

    float a = u_is0 ? 0.f : -1e30f;

    unsigned zq[16];
    #pragma unroll
    for (int j = 0; j < 16; ++j) zq[j] = gload4(Zn + (size_t)(1 + j) * 256);

    for (int d0 = 1; d0 < 361; d0 += 16) {
        const char* pn = Zn + (size_t)(d0 + 16) * 256;   // next group's rows
        #pragma unroll
        for (int j = 0; j < 16; ++j) {
            const int d = d0 + j;
            asm volatile("s_waitcnt vmcnt(15)");         // oldest ring slot ready
            asm volatile("" : "+v"(zq[j]));              // pin wait->use order
            unsigned zv = zq[j];
            zq[j] = gload4(pn + (size_t)j * 256);        // refill row d+16
            union { unsigned u32; __half2 h2; } cv; cv.u32 = zv;
            float2 w = __half22float2(cv.h2);            // .x blank, .y emit
            float av = __shfl_up(a, 1);                  // a_{u-1}(d-1)
            float b  = a + w.x;                          // blank from (t-1,u)
            float e  = av + (u_is0 ? -1e30f : w.y);      // emit from (t,u-1)
            float nn = lae2(b, e);
            a = ((unsigned)(d - u) < len_t) ? nn : a;
        }
    }

    if (u == ui) {
        const unsigned* Zb = Z + (size_t)n * SKROWS * 64;
        unsigned wf = Zb[(size_t)(ti + ui + 1) * 64 + ui];   // final blank cell
        union { unsigned u32; __half2 h2; } cf; cf.u32 = wf;
        float blf = __half22float2(cf.h2).x;
        losses[n] = -(a + blf) * LN2;
    }
    __syncthreads();
    if (tid == 0) {
        float s = 0.f;
        #pragma unroll
        for (int i = 0; i < N_; ++i) s += losses[i];
        out[0] = s * (1.0f / N_);
    }
}

extern "C" void kernel_launch(void* const* d_in, const int* in_sizes, int n_in,
                              void* d_out, int out_size, void* d_ws, size_t ws_size,
                              hipStream_t stream)
{
    const float* enc         = (const float*)d_in[0];
    const float* dec         = (const float*)d_in[1];
    const int*   targets     = (const int*)d_in[2];
    const int*   inputs_len  = (const int*)d_in[3];
    const int*   targets_len = (const int*)d_in[4];
    const float* Wj          = (const float*)d_in[5];
    const float* bj          = (const float*)d_in[6];
    const float* Wo          = (const float*)d_in[7];
    const float* bo          = (const float*)d_in[8];
    float* out = (float*)d_out;

    char* ws = (char*)d_ws;
    float*          encp  = (float*)(ws + 0);                // 2400*512 f32 = 4,915,200
    float*          decp  = (float*)(ws + 4915200);          // 488*512 f32  =   999,424
    unsigned*       Z     = (unsigned*)(ws + 5914624);       // 8*384*64 half2 = 786,432
    unsigned short* WjT   = (unsigned short*)(ws + 6701056); // 512*320 bf16 =   327,680
    unsigned short* WoT2  = (unsigned short*)(ws + 7028736); // 128*512 bf16 =   131,072
    float*          bosum = (float*)(ws + 7159872);          // 128 f32

    hipMemsetAsync(bosum, 0, VOC * sizeof(float), stream);
    convert_w<<<224, 256, 0, stream>>>(Wj, Wo, WjT, WoT2, bosum);
    proj_mfma<<<184, 256, 0, stream>>>(enc, dec, WjT, bj, encp, decp);
    joint_mfma<<<2400, 256, 0, stream>>>(encp, decp, WoT2, bo, bosum, targets, (unsigned short*)Z);
    dp_kernel<<<1, 512, 0, stream>>>(Z, inputs_len, targets_len, out);
}

// Round 11
// 184.559 us; speedup vs baseline: 1.0184x; 1.0184x over previous
//
#include <hip/hip_runtime.h>
#include <hip/hip_bf16.h>
#include <hip/hip_fp16.h>

#define N_   8
#define T_   300
#define U_   60
#define U1_  61
#define EENC 320
#define NHID 512
#define VOC  128
#define SKROWS 384
#define INV_LN2 1.4426950408889634f
#define LN2 0.6931471805599453f
#define SCALE2 2.8853900817779268f   // 2*log2(e)

typedef __attribute__((ext_vector_type(8))) short bf16x8;
typedef __attribute__((ext_vector_type(4))) float f32x4;

__device__ __forceinline__ unsigned short f2bf(float f) {
    unsigned int u = __float_as_uint(f);
    u += 0x7fff + ((u >> 16) & 1);          // RNE
    return (unsigned short)(u >> 16);
}

// log-add-exp in log2 domain, NaN/inf-proof: fminf returns the non-NaN operand,
// so a rogue inf/NaN operand degrades to max(x,y) instead of NaN.
// QUARANTINE (do not reintroduce without isolated proof): DPP wave_shr (invalid
// on CDNA4, R6), __builtin_amdgcn_logf / __builtin_amdgcn_exp2f inside this
// function (R7/R8 reds), cvt_pk sigma-pack (R8 red), pre-swizzled WoT2s +
// global_load_lds B-staging (R5 red), joint double-buffer (R10: VGPR 48->76,
// occupancy 38->25%, joint 50.5->61.1 us).
__device__ __forceinline__ float lae2(float x, float y) {
    float m = fmaxf(x, y);
    float d = fminf(fabsf(x - y), 1e30f);
    return m + log2f(1.f + exp2f(-d));
}

__device__ __forceinline__ unsigned gload4(const void* p) {
    unsigned v;
    asm volatile("global_load_dword %0, %1, off" : "=v"(v) : "v"(p) : "memory");
    return v;
}

// ---- transpose-convert: WjT[512][320]=bf(Wj^T); WoT2[128][512]=bf(-2*Wo^T); bosum[c]=sum_k Wo[k][c] ----
__global__ __launch_bounds__(256) void convert_w(
    const float* __restrict__ Wj, const float* __restrict__ Wo,
    unsigned short* __restrict__ WjT, unsigned short* __restrict__ WoT2,
    float* __restrict__ bosum)
{
    __shared__ float tile[32][33];
    int bid = blockIdx.x;
    const float* S; unsigned short* D; int k0, c0, K, C; bool isWo;
    if (bid < 160) { S = Wj; D = WjT; K = 320; C = 512; k0 = (bid >> 4) * 32; c0 = (bid & 15) * 32; isWo = false; }
    else { bid -= 160; S = Wo; D = WoT2; K = 512; C = 128; k0 = (bid >> 2) * 32; c0 = (bid & 3) * 32; isWo = true; }
    const int tx = threadIdx.x & 31, ty = threadIdx.x >> 5;
    float part = 0.f;
    #pragma unroll
    for (int i = 0; i < 32; i += 8) {
        float v = S[(k0 + ty + i) * C + c0 + tx];
        tile[ty + i][tx] = v;
        part += v;
    }
    __syncthreads();
    const float mulf = isWo ? -2.f : 1.f;
    #pragma unroll
    for (int i = 0; i < 32; i += 8)
        D[(c0 + ty + i) * K + k0 + tx] = f2bf(mulf * tile[tx][ty + i]);
    if (isWo) atomicAdd(&bosum[c0 + tx], part);
}

// ---- projection GEMM, 64x128 tiles: C[R,512] = exp2((X[R,320] @ Wj + b) * 2log2e) ----
// Stores EXP2 of the scaled preactivation: joint kernel then needs only
// sigma = rcp(fma(E,D,1)) per element (exp2(e+d) = exp2(e)*exp2(d)).
__global__ __launch_bounds__(256) void proj_mfma(
    const float* __restrict__ Xe, const float* __restrict__ Xd,
    const unsigned short* __restrict__ BT,
    const float* __restrict__ bj,
    float* __restrict__ Ce, float* __restrict__ Cd)
{
    __shared__ short lA[64 * 64];
    __shared__ short lB[128 * 64];
    int bid = blockIdx.x;
    const float* X; float* Cp; const float* bias; int R;
    if (bid < 152) { X = Xe; Cp = Ce; bias = nullptr; R = N_ * T_; }
    else { bid -= 152; X = Xd; Cp = Cd; bias = bj; R = N_ * U1_; }
    const int tid = threadIdx.x, lane = tid & 63, wave = tid >> 6;
    const int rb = bid >> 2, cb = bid & 3;
    const int rh = wave & 1, ch = wave >> 1;
    const int sr = tid >> 3, sg = tid & 7;
    const int frow = lane & 15, fg = lane >> 4, quad = lane >> 4;

    f32x4 acc[2][4];
    f32x4 z = {0.f, 0.f, 0.f, 0.f};
    #pragma unroll
    for (int a = 0; a < 2; ++a)
        #pragma unroll
        for (int b = 0; b < 4; ++b) acc[a][b] = z;

    for (int s = 0; s < 5; ++s) {
        __syncthreads();
        #pragma unroll
        for (int p = 0; p < 2; ++p) {
            int row = sr + p * 32;
            int grow = rb * 64 + row; if (grow >= R) grow = R - 1;
            const float* xp = X + grow * EENC + s * 64 + sg * 8;
            float4 x0 = *(const float4*)xp, x1 = *(const float4*)(xp + 4);
            bf16x8 va;
            va[0] = (short)f2bf(x0.x); va[1] = (short)f2bf(x0.y);
            va[2] = (short)f2bf(x0.z); va[3] = (short)f2bf(x0.w);
            va[4] = (short)f2bf(x1.x); va[5] = (short)f2bf(x1.y);
            va[6] = (short)f2bf(x1.z); va[7] = (short)f2bf(x1.w);
            *(bf16x8*)&lA[row * 64 + ((sg ^ (row & 7)) << 3)] = va;
        }
        #pragma unroll
        for (int p = 0; p < 4; ++p) {
            int col = sr + p * 32;
            bf16x8 vb = *(const bf16x8*)(BT + (cb * 128 + col) * EENC + s * 64 + sg * 8);
            *(bf16x8*)&lB[col * 64 + ((sg ^ (col & 7)) << 3)] = vb;
        }
        __syncthreads();
        #pragma unroll
        for (int ks = 0; ks < 2; ++ks) {
            int g = fg + ks * 4;
            bf16x8 af[2], bf[4];
            #pragma unroll
            for (int rt = 0; rt < 2; ++rt) {
                int row = rh * 32 + rt * 16 + frow;
                af[rt] = *(const bf16x8*)&lA[row * 64 + ((g ^ (row & 7)) << 3)];
            }
            #pragma unroll
            for (int c = 0; c < 4; ++c) {
                int col = ch * 64 + c * 16 + frow;
                bf[c] = *(const bf16x8*)&lB[col * 64 + ((g ^ (col & 7)) << 3)];
            }
            #pragma unroll
            for (int rt = 0; rt < 2; ++rt)
                #pragma unroll
                for (int c = 0; c < 4; ++c)
                    acc[rt][c] = __builtin_amdgcn_mfma_f32_16x16x32_bf16(af[rt], bf[c], acc[rt][c], 0, 0, 0);
        }
    }
    #pragma unroll
    for (int rt = 0; rt < 2; ++rt) {
        int grow0 = rb * 64 + rh * 32 + rt * 16 + quad * 4;
        #pragma unroll
        for (int c = 0; c < 4; ++c) {
            int col = cb * 128 + ch * 64 + c * 16 + frow;
            float b = bias ? bias[col] : 0.f;
            #pragma unroll
            for (int r = 0; r < 4; ++r) {
                int gr = grow0 + r;
                if (gr < R)
                    Cp[gr * NHID + col] = __builtin_amdgcn_exp2f((acc[rt][c][r] + b) * SCALE2);
            }
        }
    }
}

// σ-pack helper: 8x sigma = rcp(fma(E,D,1)) -> bf16x8 (trunc-to-nearest) -> swizzled LDS store
__device__ __forceinline__ void sigstore(short* lAp, float4 ee0, float4 ee1,
                                         float4 dd0, float4 dd1, int row, int sg)
{
    float s0 = __builtin_amdgcn_rcpf(__builtin_fmaf(ee0.x, dd0.x, 1.f));
    float s1 = __builtin_amdgcn_rcpf(__builtin_fmaf(ee0.y, dd0.y, 1.f));
    float s2 = __builtin_amdgcn_rcpf(__builtin_fmaf(ee0.z, dd0.z, 1.f));
    float s3 = __builtin_amdgcn_rcpf(__builtin_fmaf(ee0.w, dd0.w, 1.f));
    float s4 = __builtin_amdgcn_rcpf(__builtin_fmaf(ee1.x, dd1.x, 1.f));
    float s5 = __builtin_amdgcn_rcpf(__builtin_fmaf(ee1.y, dd1.y, 1.f));
    float s6 = __builtin_amdgcn_rcpf(__builtin_fmaf(ee1.z, dd1.z, 1.f));
    float s7 = __builtin_amdgcn_rcpf(__builtin_fmaf(ee1.w, dd1.w, 1.f));
    unsigned b0 = __float_as_uint(s0) + 0x8000u, b1 = __float_as_uint(s1) + 0x8000u;
    unsigned b2 = __float_as_uint(s2) + 0x8000u, b3 = __float_as_uint(s3) + 0x8000u;
    unsigned b4 = __float_as_uint(s4) + 0x8000u, b5 = __float_as_uint(s5) + 0x8000u;
    unsigned b6 = __float_as_uint(s6) + 0x8000u, b7 = __float_as_uint(s7) + 0x8000u;
    union { unsigned u4[4]; bf16x8 v; } va;
    va.u4[0] = __builtin_amdgcn_perm(b1, b0, 0x07060302);
    va.u4[1] = __builtin_amdgcn_perm(b3, b2, 0x07060302);
    va.u4[2] = __builtin_amdgcn_perm(b5, b4, 0x07060302);
    va.u4[3] = __builtin_amdgcn_perm(b7, b6, 0x07060302);
    *(bf16x8*)&lAp[row * 64 + ((sg ^ (row & 7)) << 3)] = va.v;
}

// ---- joint v7: one (n,t) per block; sigma = rcp(fma(E,D,1)) with E,D
//      pre-exponentiated in proj. Single-buffer 2-barrier slice loop — R10's
//      double-buffer A/B showed that costs occupancy (3->2 blocks/CU) and loses. ----
__global__ __launch_bounds__(256, 5) void joint_mfma(
    const float* __restrict__ encp,          // [2400][512], exp2 of scaled enc preact
    const float* __restrict__ decp,          // [488][512], exp2 of scaled dec preact (+bj)
    const unsigned short* __restrict__ WoT2, // [128][512] bf16 = -2*Wo^T
    const float* __restrict__ bo, const float* __restrict__ bosum,
    const int* __restrict__ targets,
    unsigned short* __restrict__ Zs)
{
    __shared__ short lA[64 * 64];            // 8 KB
    __shared__ short lB[128 * 64];           // 16 KB
    __shared__ float bo_s[VOC];
    __shared__ int   lab_s[U_];

    const int tid = threadIdx.x, lane = tid & 63, wave = tid >> 6;  // wave 0..3
    const int nt = blockIdx.x;
    const int n = nt / T_, t0 = nt - n * T_;
    if (tid < VOC) bo_s[tid] = bo[tid] + bosum[tid];
    else if (tid < VOC + U_) lab_s[tid - VOC] = targets[n * U_ + (tid - VOC)];

    const int frow = lane & 15, quad = lane >> 4;
    const int sg = tid & 7, sr = tid >> 3;   // sr 0..31, k-octet sg

    f32x4 acc[8];
    f32x4 z = {0.f, 0.f, 0.f, 0.f};
    #pragma unroll
    for (int c = 0; c < 8; ++c) acc[c] = z;

    const int ua0 = min(sr, U_);
    const int ua1 = min(sr + 32, U_);
    const float* dbase0 = decp + (size_t)(n * U1_ + ua0) * NHID + sg * 8;
    const float* dbase1 = decp + (size_t)(n * U1_ + ua1) * NHID + sg * 8;
    const float* ebase  = encp + (size_t)nt * NHID + sg * 8;
    const unsigned short* wbase = WoT2 + sg * 8;

    // prefetch registers (slice s data, loaded one iteration ahead)
    float4 e0, e1, d00, d01, d10, d11;
    bf16x8 vb0, vb1, vb2, vb3;
    e0  = *(const float4*)ebase;        e1  = *(const float4*)(ebase + 4);
    d00 = *(const float4*)dbase0;       d01 = *(const float4*)(dbase0 + 4);
    d10 = *(const float4*)dbase1;       d11 = *(const float4*)(dbase1 + 4);
    vb0 = *(const bf16x8*)(wbase + (size_t)(sr +  0) * NHID);
    vb1 = *(const bf16x8*)(wbase + (size_t)(sr + 32) * NHID);
    vb2 = *(const bf16x8*)(wbase + (size_t)(sr + 64) * NHID);
    vb3 = *(const bf16x8*)(wbase + (size_t)(sr + 96) * NHID);

    for (int s = 0; s < 8; ++s) {            // K=512, slices of 64
        __syncthreads();                     // prev MFMA done reading lA/lB
        // ---- B staging from regs ----
        { int col = sr;      *(bf16x8*)&lB[col * 64 + ((sg ^ (col & 7)) << 3)] = vb0; }
        { int col = sr + 32; *(bf16x8*)&lB[col * 64 + ((sg ^ (col & 7)) << 3)] = vb1; }
        { int col = sr + 64; *(bf16x8*)&lB[col * 64 + ((sg ^ (col & 7)) << 3)] = vb2; }
        { int col = sr + 96; *(bf16x8*)&lB[col * 64 + ((sg ^ (col & 7)) << 3)] = vb3; }
        // ---- A sigma staging: rows sr and sr+32 (enc chunk shared) ----
        sigstore(lA, e0, e1, d00, d01, sr,      sg);
        sigstore(lA, e0, e1, d10, d11, sr + 32, sg);
        __syncthreads();                     // lA/lB ready
        // ---- issue next-slice loads; latency covered by MFMA phase ----
        if (s < 7) {
            const int o = (s + 1) * 64;
            e0  = *(const float4*)(ebase + o);      e1  = *(const float4*)(ebase + o + 4);
            d00 = *(const float4*)(dbase0 + o);     d01 = *(const float4*)(dbase0 + o + 4);
            d10 = *(const float4*)(dbase1 + o);     d11 = *(const float4*)(dbase1 + o + 4);
            vb0 = *(const bf16x8*)(wbase + (size_t)(sr +  0) * NHID + o);
            vb1 = *(const bf16x8*)(wbase + (size_t)(sr + 32) * NHID + o);
            vb2 = *(const bf16x8*)(wbase + (size_t)(sr + 64) * NHID + o);
            vb3 = *(const bf16x8*)(wbase + (size_t)(sr + 96) * NHID + o);
        }
        // ---- MFMA: wave covers rows wave*16..+15, all 128 cols ----
        __builtin_amdgcn_s_setprio(1);
        #pragma unroll
        for (int ks = 0; ks < 2; ++ks) {
            const int g = ks * 4 + quad;
            int ar = wave * 16 + frow;
            bf16x8 af = *(const bf16x8*)&lA[ar * 64 + ((g ^ (ar & 7)) << 3)];
            #pragma unroll
            for (int c = 0; c < 8; ++c) {
                int col = c * 16 + frow;
                const bf16x8 bfr = *(const bf16x8*)&lB[col * 64 + ((g ^ (col & 7)) << 3)];
                acc[c] = __builtin_amdgcn_mfma_f32_16x16x32_bf16(af, bfr, acc[c], 0, 0, 0);
            }
        }
        __builtin_amdgcn_s_setprio(0);
    }

    // ---- epilogue: bias + wave-local per-row LSE; fp16 skew Z output ----
    #pragma unroll
    for (int c = 0; c < 8; ++c) {
        float b = bo_s[c * 16 + frow];
        #pragma unroll
        for (int r = 0; r < 4; ++r) acc[c][r] += b;
    }
    float mx[4], sm[4];
    #pragma unroll
    for (int r = 0; r < 4; ++r) {
        float m = acc[0][r];
        #pragma unroll
        for (int c = 1; c < 8; ++c) m = fmaxf(m, acc[c][r]);
        mx[r] = m;
    }
    #pragma unroll
    for (int off = 1; off < 16; off <<= 1)
        #pragma unroll
        for (int r = 0; r < 4; ++r) mx[r] = fmaxf(mx[r], __shfl_xor(mx[r], off));
    #pragma unroll
    for (int r = 0; r < 4; ++r) {
        float ss = 0.f;
        #pragma unroll
        for (int c = 0; c < 8; ++c) ss += __expf(acc[c][r] - mx[r]);
        sm[r] = ss;
    }
    #pragma unroll
    for (int off = 1; off < 16; off <<= 1)
        #pragma unroll
        for (int r = 0; r < 4; ++r) sm[r] += __shfl_xor(sm[r], off);

    #pragma unroll
    for (int r = 0; r < 4; ++r) {
        float lse = mx[r] + __logf(sm[r]);
        int urow = wave * 16 + quad * 4 + r;             // 0..63
        size_t rowz = (size_t)(n * SKROWS + t0 + urow + 1) * 64;
        if (urow < U1_ && frow == 0) {
            __half hh = __float2half_rn((acc[0][r] - lse) * INV_LN2);
            Zs[(rowz + urow) * 2] = __half_as_ushort(hh);
        }
        if (urow < U_) {
            int lab = lab_s[urow];
            if (frow == (lab & 15)) {
                int cw = lab >> 4;
                float pick = acc[0][r];
                #pragma unroll
                for (int c = 1; c < 8; ++c) if (c == cw) pick = acc[c][r];
                __half hh = __float2half_rn((pick - lse) * INV_LN2);
                Zs[(rowz + urow + 1) * 2 + 1] = __half_as_ushort(hh);
            }
        }
    }
}

// ---- dp v4: single block, 512 thr; ONE BATCH PER WAVE (8 working waves),
//      one u-value per lane (61 active lanes/wave), 16-deep dword prefetch ring. ----
__global__ __launch_bounds__(512) void dp_kernel(
    const unsigned* __restrict__ Z,
    const int* __restrict__ inputs_len, const int* __restrict__ targets_len,
    float* __restrict__ out)
{
    __shared__ float losses[N_];
    const int tid = threadIdx.x;
    const int n = tid >> 6;                  // wave index = batch index
    const int u = tid & 63;                  // one u per lane; u<61 meaningful
    const bool u_is0 = (u == 0);

    const unsigned len_t = (unsigned)inputs_len[n];
    const int ui = targets_len[n];
    const int ti = (int)len_t - 1;

    // lane's column of batch n: 4 B per (d,u) half2 cell; row pitch 256 B
    const char* Zn = (const char*)(Z + (size_t)n * SKROWS * 64) + u * 4;

    float a = u_is0 ? 0.f : -1e30f;

    unsigned zq[16];
    #pragma unroll
    for (int j = 0; j < 16; ++j) zq[j] = gload4(Zn + (size_t)(1 + j) * 256);

    for (int d0 = 1; d0 < 361; d0 += 16) {
        const char* pn = Zn + (size_t)(d0 + 16) * 256;   // next group's rows
        #pragma unroll
        for (int j = 0; j < 16; ++j) {
            const int d = d0 + j;
            asm volatile("s_waitcnt vmcnt(15)");         // oldest ring slot ready
            asm volatile("" : "+v"(zq[j]));              // pin wait->use order
            unsigned zv = zq[j];
            zq[j] = gload4(pn + (size_t)j * 256);        // refill row d+16
            union { unsigned u32; __half2 h2; } cv; cv.u32 = zv;
            float2 w = __half22float2(cv.h2);            // .x blank, .y emit
            float av = __shfl_up(a, 1);                  // a_{u-1}(d-1)
            float b  = a + w.x;                          // blank from (t-1,u)
            float e  = av + (u_is0 ? -1e30f : w.y);      // emit from (t,u-1)
            float nn = lae2(b, e);
            a = ((unsigned)(d - u) < len_t) ? nn : a;
        }
    }

    if (u == ui) {
        const unsigned* Zb = Z + (size_t)n * SKROWS * 64;
        unsigned wf = Zb[(size_t)(ti + ui + 1) * 64 + ui];   // final blank cell
        union { unsigned u32; __half2 h2; } cf; cf.u32 = wf;
        float blf = __half22float2(cf.h2).x;
        losses[n] = -(a + blf) * LN2;
    }
    __syncthreads();
    if (tid == 0) {
        float s = 0.f;
        #pragma unroll
        for (int i = 0; i < N_; ++i) s += losses[i];
        out[0] = s * (1.0f / N_);
    }
}

extern "C" void kernel_launch(void* const* d_in, const int* in_sizes, int n_in,
                              void* d_out, int out_size, void* d_ws, size_t ws_size,
                              hipStream_t stream)
{
    const float* enc         = (const float*)d_in[0];
    const float* dec         = (const float*)d_in[1];
    const int*   targets     = (const int*)d_in[2];
    const int*   inputs_len  = (const int*)d_in[3];
    const int*   targets_len = (const int*)d_in[4];
    const float* Wj          = (const float*)d_in[5];
    const float* bj          = (const float*)d_in[6];
    const float* Wo          = (const float*)d_in[7];
    const float* bo          = (const float*)d_in[8];
    float* out = (float*)d_out;

    char* ws = (char*)d_ws;
    float*          encp  = (float*)(ws + 0);                // 2400*512 f32 = 4,915,200
    float*          decp  = (float*)(ws + 4915200);          // 488*512 f32  =   999,424
    unsigned*       Z     = (unsigned*)(ws + 5914624);       // 8*384*64 half2 = 786,432
    unsigned short* WjT   = (unsigned short*)(ws + 6701056); // 512*320 bf16 =   327,680
    unsigned short* WoT2  = (unsigned short*)(ws + 7028736); // 128*512 bf16 =   131,072
    float*          bosum = (float*)(ws + 7159872);          // 128 f32

    hipMemsetAsync(bosum, 0, VOC * sizeof(float), stream);
    convert_w<<<224, 256, 0, stream>>>(Wj, Wo, WjT, WoT2, bosum);
    proj_mfma<<<184, 256, 0, stream>>>(enc, dec, WjT, bj, encp, decp);
    joint_mfma<<<2400, 256, 0, stream>>>(encp, decp, WoT2, bo, bosum, targets, (unsigned short*)Z);
    dp_kernel<<<1, 512, 0, stream>>>(Z, inputs_len, targets_len, out);
}

// Round 12
// 178.034 us; speedup vs baseline: 1.0557x; 1.0366x over previous
//
#include <hip/hip_runtime.h>
#include <hip/hip_bf16.h>
#include <hip/hip_fp16.h>

#define N_   8
#define T_   300
#define U_   60
#define U1_  61
#define EENC 320
#define NHID 512
#define VOC  128
#define SKROWS 384
#define INV_LN2 1.4426950408889634f
#define LN2 0.6931471805599453f
#define SCALE2 2.8853900817779268f   // 2*log2(e)

typedef __attribute__((ext_vector_type(8))) short bf16x8;
typedef __attribute__((ext_vector_type(4))) float f32x4;

__device__ __forceinline__ unsigned short f2bf(float f) {
    unsigned int u = __float_as_uint(f);
    u += 0x7fff + ((u >> 16) & 1);          // RNE
    return (unsigned short)(u >> 16);
}

// log-add-exp in log2 domain, NaN/inf-proof: fminf returns the non-NaN operand,
// so a rogue inf/NaN operand degrades to max(x,y) instead of NaN.
// QUARANTINE (do not reintroduce without isolated proof): DPP wave_shr (invalid
// on CDNA4, R6), __builtin_amdgcn_logf / __builtin_amdgcn_exp2f inside this
// function (R7/R8 reds — suspected mechanism: codegen perturbation adds VMEM
// (spills) inside dp's loop, breaking the hand-counted vmcnt(15) ring),
// cvt_pk sigma-pack (R8 red), pre-swizzled WoT2s + global_load_lds B-staging
// (R5 red), joint double-buffer (R10: occupancy 38->25%, 50.5->61.1 us).
__device__ __forceinline__ float lae2(float x, float y) {
    float m = fmaxf(x, y);
    float d = fminf(fabsf(x - y), 1e30f);
    return m + log2f(1.f + exp2f(-d));
}

__device__ __forceinline__ unsigned gload4(const void* p) {
    unsigned v;
    asm volatile("global_load_dword %0, %1, off" : "=v"(v) : "v"(p) : "memory");
    return v;
}

// ---- transpose-convert: WjT[512][320]=bf(Wj^T); WoT2[128][512]=bf(-2*Wo^T); bosum[c]=sum_k Wo[k][c] ----
__global__ __launch_bounds__(256) void convert_w(
    const float* __restrict__ Wj, const float* __restrict__ Wo,
    unsigned short* __restrict__ WjT, unsigned short* __restrict__ WoT2,
    float* __restrict__ bosum)
{
    __shared__ float tile[32][33];
    int bid = blockIdx.x;
    const float* S; unsigned short* D; int k0, c0, K, C; bool isWo;
    if (bid < 160) { S = Wj; D = WjT; K = 320; C = 512; k0 = (bid >> 4) * 32; c0 = (bid & 15) * 32; isWo = false; }
    else { bid -= 160; S = Wo; D = WoT2; K = 512; C = 128; k0 = (bid >> 2) * 32; c0 = (bid & 3) * 32; isWo = true; }
    const int tx = threadIdx.x & 31, ty = threadIdx.x >> 5;
    float part = 0.f;
    #pragma unroll
    for (int i = 0; i < 32; i += 8) {
        float v = S[(k0 + ty + i) * C + c0 + tx];
        tile[ty + i][tx] = v;
        part += v;
    }
    __syncthreads();
    const float mulf = isWo ? -2.f : 1.f;
    #pragma unroll
    for (int i = 0; i < 32; i += 8)
        D[(c0 + ty + i) * K + k0 + tx] = f2bf(mulf * tile[tx][ty + i]);
    if (isWo) atomicAdd(&bosum[c0 + tx], part);
}

// ---- projection GEMM, 64x128 tiles: C[R,512] = exp2((X[R,320] @ Wj + b) * 2log2e) ----
// Stores EXP2 of the scaled preactivation: joint kernel then needs only
// sigma = rcp(fma(E,D,1)) per element (exp2(e+d) = exp2(e)*exp2(d)).
__global__ __launch_bounds__(256) void proj_mfma(
    const float* __restrict__ Xe, const float* __restrict__ Xd,
    const unsigned short* __restrict__ BT,
    const float* __restrict__ bj,
    float* __restrict__ Ce, float* __restrict__ Cd)
{
    __shared__ short lA[64 * 64];
    __shared__ short lB[128 * 64];
    int bid = blockIdx.x;
    const float* X; float* Cp; const float* bias; int R;
    if (bid < 152) { X = Xe; Cp = Ce; bias = nullptr; R = N_ * T_; }
    else { bid -= 152; X = Xd; Cp = Cd; bias = bj; R = N_ * U1_; }
    const int tid = threadIdx.x, lane = tid & 63, wave = tid >> 6;
    const int rb = bid >> 2, cb = bid & 3;
    const int rh = wave & 1, ch = wave >> 1;
    const int sr = tid >> 3, sg = tid & 7;
    const int frow = lane & 15, fg = lane >> 4, quad = lane >> 4;

    f32x4 acc[2][4];
    f32x4 z = {0.f, 0.f, 0.f, 0.f};
    #pragma unroll
    for (int a = 0; a < 2; ++a)
        #pragma unroll
        for (int b = 0; b < 4; ++b) acc[a][b] = z;

    for (int s = 0; s < 5; ++s) {
        __syncthreads();
        #pragma unroll
        for (int p = 0; p < 2; ++p) {
            int row = sr + p * 32;
            int grow = rb * 64 + row; if (grow >= R) grow = R - 1;
            const float* xp = X + grow * EENC + s * 64 + sg * 8;
            float4 x0 = *(const float4*)xp, x1 = *(const float4*)(xp + 4);
            bf16x8 va;
            va[0] = (short)f2bf(x0.x); va[1] = (short)f2bf(x0.y);
            va[2] = (short)f2bf(x0.z); va[3] = (short)f2bf(x0.w);
            va[4] = (short)f2bf(x1.x); va[5] = (short)f2bf(x1.y);
            va[6] = (short)f2bf(x1.z); va[7] = (short)f2bf(x1.w);
            *(bf16x8*)&lA[row * 64 + ((sg ^ (row & 7)) << 3)] = va;
        }
        #pragma unroll
        for (int p = 0; p < 4; ++p) {
            int col = sr + p * 32;
            bf16x8 vb = *(const bf16x8*)(BT + (cb * 128 + col) * EENC + s * 64 + sg * 8);
            *(bf16x8*)&lB[col * 64 + ((sg ^ (col & 7)) << 3)] = vb;
        }
        __syncthreads();
        #pragma unroll
        for (int ks = 0; ks < 2; ++ks) {
            int g = fg + ks * 4;
            bf16x8 af[2], bf[4];
            #pragma unroll
            for (int rt = 0; rt < 2; ++rt) {
                int row = rh * 32 + rt * 16 + frow;
                af[rt] = *(const bf16x8*)&lA[row * 64 + ((g ^ (row & 7)) << 3)];
            }
            #pragma unroll
            for (int c = 0; c < 4; ++c) {
                int col = ch * 64 + c * 16 + frow;
                bf[c] = *(const bf16x8*)&lB[col * 64 + ((g ^ (col & 7)) << 3)];
            }
            #pragma unroll
            for (int rt = 0; rt < 2; ++rt)
                #pragma unroll
                for (int c = 0; c < 4; ++c)
                    acc[rt][c] = __builtin_amdgcn_mfma_f32_16x16x32_bf16(af[rt], bf[c], acc[rt][c], 0, 0, 0);
        }
    }
    #pragma unroll
    for (int rt = 0; rt < 2; ++rt) {
        int grow0 = rb * 64 + rh * 32 + rt * 16 + quad * 4;
        #pragma unroll
        for (int c = 0; c < 4; ++c) {
            int col = cb * 128 + ch * 64 + c * 16 + frow;
            float b = bias ? bias[col] : 0.f;
            #pragma unroll
            for (int r = 0; r < 4; ++r) {
                int gr = grow0 + r;
                if (gr < R)
                    Cp[gr * NHID + col] = __builtin_amdgcn_exp2f((acc[rt][c][r] + b) * SCALE2);
            }
        }
    }
}

// σ-pack helper: 8x sigma = rcp(fma(E,D,1)) -> bf16x8 (trunc-to-nearest) -> swizzled LDS store
__device__ __forceinline__ void sigstore(short* lAp, float4 ee0, float4 ee1,
                                         float4 dd0, float4 dd1, int row, int sg)
{
    float s0 = __builtin_amdgcn_rcpf(__builtin_fmaf(ee0.x, dd0.x, 1.f));
    float s1 = __builtin_amdgcn_rcpf(__builtin_fmaf(ee0.y, dd0.y, 1.f));
    float s2 = __builtin_amdgcn_rcpf(__builtin_fmaf(ee0.z, dd0.z, 1.f));
    float s3 = __builtin_amdgcn_rcpf(__builtin_fmaf(ee0.w, dd0.w, 1.f));
    float s4 = __builtin_amdgcn_rcpf(__builtin_fmaf(ee1.x, dd1.x, 1.f));
    float s5 = __builtin_amdgcn_rcpf(__builtin_fmaf(ee1.y, dd1.y, 1.f));
    float s6 = __builtin_amdgcn_rcpf(__builtin_fmaf(ee1.z, dd1.z, 1.f));
    float s7 = __builtin_amdgcn_rcpf(__builtin_fmaf(ee1.w, dd1.w, 1.f));
    unsigned b0 = __float_as_uint(s0) + 0x8000u, b1 = __float_as_uint(s1) + 0x8000u;
    unsigned b2 = __float_as_uint(s2) + 0x8000u, b3 = __float_as_uint(s3) + 0x8000u;
    unsigned b4 = __float_as_uint(s4) + 0x8000u, b5 = __float_as_uint(s5) + 0x8000u;
    unsigned b6 = __float_as_uint(s6) + 0x8000u, b7 = __float_as_uint(s7) + 0x8000u;
    union { unsigned u4[4]; bf16x8 v; } va;
    va.u4[0] = __builtin_amdgcn_perm(b1, b0, 0x07060302);
    va.u4[1] = __builtin_amdgcn_perm(b3, b2, 0x07060302);
    va.u4[2] = __builtin_amdgcn_perm(b5, b4, 0x07060302);
    va.u4[3] = __builtin_amdgcn_perm(b7, b6, 0x07060302);
    *(bf16x8*)&lAp[row * 64 + ((sg ^ (row & 7)) << 3)] = va.v;
}

// ---- joint v10: 512 thr, TWO nt per block (grid 1200). B tile + dec row loads
//      shared by both nt: B staging passes 4->2 per thread, dec load 1 per
//      thread serves both nt. Sigstore math / swizzles / MFMA layout / epilogue
//      byte-identical to v7 green. Waves 0-3 -> nt0, waves 4-7 -> nt0+1. ----
__global__ __launch_bounds__(512, 4) void joint_mfma(
    const float* __restrict__ encp,          // [2400][512], exp2 of scaled enc preact
    const float* __restrict__ decp,          // [488][512], exp2 of scaled dec preact (+bj)
    const unsigned short* __restrict__ WoT2, // [128][512] bf16 = -2*Wo^T
    const float* __restrict__ bo, const float* __restrict__ bosum,
    const int* __restrict__ targets,
    unsigned short* __restrict__ Zs)
{
    __shared__ short lA[2][64 * 64];         // 16 KB (one 64x64 A tile per nt)
    __shared__ short lB[128 * 64];           // 16 KB (shared by both nt)
    __shared__ float bo_s[VOC];
    __shared__ int   lab_s[U_];

    const int tid = threadIdx.x, lane = tid & 63, wave = tid >> 6;  // wave 0..7
    const int nt0 = 2 * blockIdx.x;
    const int n = nt0 / T_, t0 = nt0 - n * T_;   // t0 <= 298, so nt0+1 same batch
    if (tid < VOC) bo_s[tid] = bo[tid] + bosum[tid];
    else if (tid < VOC + U_) lab_s[tid - VOC] = targets[n * U_ + (tid - VOC)];

    const int frow = lane & 15, quad = lane >> 4;
    const int sg = tid & 7, sr = tid >> 3;   // sr 0..63, k-octet sg
    const int wnt = wave >> 2;               // which nt this wave computes
    const int wr  = wave & 3;                // row-quarter within the nt

    f32x4 acc[8];
    f32x4 z = {0.f, 0.f, 0.f, 0.f};
    #pragma unroll
    for (int c = 0; c < 8; ++c) acc[c] = z;

    const int ua = min(sr, U_);
    const float* dbase  = decp + (size_t)(n * U1_ + ua) * NHID + sg * 8;
    const float* ebase0 = encp + (size_t)nt0 * NHID + sg * 8;
    const float* ebase1 = ebase0 + NHID;
    const unsigned short* wbase = WoT2 + sg * 8;

    // prefetch registers (slice s data, loaded one iteration ahead)
    float4 e0, e1, f0, f1, d0, d1;
    bf16x8 vb0, vb1;
    e0 = *(const float4*)ebase0;        e1 = *(const float4*)(ebase0 + 4);
    f0 = *(const float4*)ebase1;        f1 = *(const float4*)(ebase1 + 4);
    d0 = *(const float4*)dbase;         d1 = *(const float4*)(dbase + 4);
    vb0 = *(const bf16x8*)(wbase + (size_t)(sr +  0) * NHID);
    vb1 = *(const bf16x8*)(wbase + (size_t)(sr + 64) * NHID);

    for (int s = 0; s < 8; ++s) {            // K=512, slices of 64
        __syncthreads();                     // prev MFMA done reading lA/lB
        // ---- B staging from regs: 2 passes (sr covers 0..63) ----
        { int col = sr;      *(bf16x8*)&lB[col * 64 + ((sg ^ (col & 7)) << 3)] = vb0; }
        { int col = sr + 64; *(bf16x8*)&lB[col * 64 + ((sg ^ (col & 7)) << 3)] = vb1; }
        // ---- A sigma staging: row sr of BOTH nt, same dec chunk ----
        sigstore(lA[0], e0, e1, d0, d1, sr, sg);
        sigstore(lA[1], f0, f1, d0, d1, sr, sg);
        __syncthreads();                     // lA/lB ready
        // ---- issue next-slice loads; latency covered by MFMA phase ----
        if (s < 7) {
            const int o = (s + 1) * 64;
            e0 = *(const float4*)(ebase0 + o);      e1 = *(const float4*)(ebase0 + o + 4);
            f0 = *(const float4*)(ebase1 + o);      f1 = *(const float4*)(ebase1 + o + 4);
            d0 = *(const float4*)(dbase + o);       d1 = *(const float4*)(dbase + o + 4);
            vb0 = *(const bf16x8*)(wbase + (size_t)(sr +  0) * NHID + o);
            vb1 = *(const bf16x8*)(wbase + (size_t)(sr + 64) * NHID + o);
        }
        // ---- MFMA: wave covers rows wr*16..+15 of lA[wnt], all 128 cols ----
        const short* lAp = lA[wnt];
        __builtin_amdgcn_s_setprio(1);
        #pragma unroll
        for (int ks = 0; ks < 2; ++ks) {
            const int g = ks * 4 + quad;
            int ar = wr * 16 + frow;
            bf16x8 af = *(const bf16x8*)&lAp[ar * 64 + ((g ^ (ar & 7)) << 3)];
            #pragma unroll
            for (int c = 0; c < 8; ++c) {
                int col = c * 16 + frow;
                const bf16x8 bfr = *(const bf16x8*)&lB[col * 64 + ((g ^ (col & 7)) << 3)];
                acc[c] = __builtin_amdgcn_mfma_f32_16x16x32_bf16(af, bfr, acc[c], 0, 0, 0);
            }
        }
        __builtin_amdgcn_s_setprio(0);
    }

    // ---- epilogue: bias + wave-local per-row LSE; fp16 skew Z output ----
    #pragma unroll
    for (int c = 0; c < 8; ++c) {
        float b = bo_s[c * 16 + frow];
        #pragma unroll
        for (int r = 0; r < 4; ++r) acc[c][r] += b;
    }
    float mx[4], sm[4];
    #pragma unroll
    for (int r = 0; r < 4; ++r) {
        float m = acc[0][r];
        #pragma unroll
        for (int c = 1; c < 8; ++c) m = fmaxf(m, acc[c][r]);
        mx[r] = m;
    }
    #pragma unroll
    for (int off = 1; off < 16; off <<= 1)
        #pragma unroll
        for (int r = 0; r < 4; ++r) mx[r] = fmaxf(mx[r], __shfl_xor(mx[r], off));
    #pragma unroll
    for (int r = 0; r < 4; ++r) {
        float ss = 0.f;
        #pragma unroll
        for (int c = 0; c < 8; ++c) ss += __expf(acc[c][r] - mx[r]);
        sm[r] = ss;
    }
    #pragma unroll
    for (int off = 1; off < 16; off <<= 1)
        #pragma unroll
        for (int r = 0; r < 4; ++r) sm[r] += __shfl_xor(sm[r], off);

    const int myt = t0 + wnt;                // this wave's t
    #pragma unroll
    for (int r = 0; r < 4; ++r) {
        float lse = mx[r] + __logf(sm[r]);
        int urow = wr * 16 + quad * 4 + r;               // 0..63
        size_t rowz = (size_t)(n * SKROWS + myt + urow + 1) * 64;
        if (urow < U1_ && frow == 0) {
            __half hh = __float2half_rn((acc[0][r] - lse) * INV_LN2);
            Zs[(rowz + urow) * 2] = __half_as_ushort(hh);
        }
        if (urow < U_) {
            int lab = lab_s[urow];
            if (frow == (lab & 15)) {
                int cw = lab >> 4;
                float pick = acc[0][r];
                #pragma unroll
                for (int c = 1; c < 8; ++c) if (c == cw) pick = acc[c][r];
                __half hh = __float2half_rn((pick - lse) * INV_LN2);
                Zs[(rowz + urow + 1) * 2 + 1] = __half_as_ushort(hh);
            }
        }
    }
}

// ---- dp v4: single block, 512 thr; ONE BATCH PER WAVE (8 working waves),
//      one u-value per lane (61 active lanes/wave), 16-deep dword prefetch ring.
//      DO NOT EDIT: hand-counted vmcnt(15) ring is fragile to any codegen
//      perturbation (suspected cause of R7/R8 reds). ----
__global__ __launch_bounds__(512) void dp_kernel(
    const unsigned* __restrict__ Z,
    const int* __restrict__ inputs_len, const int* __restrict__ targets_len,
    float* __restrict__ out)
{
    __shared__ float losses[N_];
    const int tid = threadIdx.x;
    const int n = tid >> 6;                  // wave index = batch index
    const int u = tid & 63;                  // one u per lane; u<61 meaningful
    const bool u_is0 = (u == 0);

    const unsigned len_t = (unsigned)inputs_len[n];
    const int ui = targets_len[n];
    const int ti = (int)len_t - 1;

    // lane's column of batch n: 4 B per (d,u) half2 cell; row pitch 256 B
    const char* Zn = (const char*)(Z + (size_t)n * SKROWS * 64) + u * 4;

    float a = u_is0 ? 0.f : -1e30f;

    unsigned zq[16];
    #pragma unroll
    for (int j = 0; j < 16; ++j) zq[j] = gload4(Zn + (size_t)(1 + j) * 256);

    for (int d0 = 1; d0 < 361; d0 += 16) {
        const char* pn = Zn + (size_t)(d0 + 16) * 256;   // next group's rows
        #pragma unroll
        for (int j = 0; j < 16; ++j) {
            const int d = d0 + j;
            asm volatile("s_waitcnt vmcnt(15)");         // oldest ring slot ready
            asm volatile("" : "+v"(zq[j]));              // pin wait->use order
            unsigned zv = zq[j];
            zq[j] = gload4(pn + (size_t)j * 256);        // refill row d+16
            union { unsigned u32; __half2 h2; } cv; cv.u32 = zv;
            float2 w = __half22float2(cv.h2);            // .x blank, .y emit
            float av = __shfl_up(a, 1);                  // a_{u-1}(d-1)
            float b  = a + w.x;                          // blank from (t-1,u)
            float e  = av + (u_is0 ? -1e30f : w.y);      // emit from (t,u-1)
            float nn = lae2(b, e);
            a = ((unsigned)(d - u) < len_t) ? nn : a;
        }
    }

    if (u == ui) {
        const unsigned* Zb = Z + (size_t)n * SKROWS * 64;
        unsigned wf = Zb[(size_t)(ti + ui + 1) * 64 + ui];   // final blank cell
        union { unsigned u32; __half2 h2; } cf; cf.u32 = wf;
        float blf = __half22float2(cf.h2).x;
        losses[n] = -(a + blf) * LN2;
    }
    __syncthreads();
    if (tid == 0) {
        float s = 0.f;
        #pragma unroll
        for (int i = 0; i < N_; ++i) s += losses[i];
        out[0] = s * (1.0f / N_);
    }
}

extern "C" void kernel_launch(void* const* d_in, const int* in_sizes, int n_in,
                              void* d_out, int out_size, void* d_ws, size_t ws_size,
                              hipStream_t stream)
{
    const float* enc         = (const float*)d_in[0];
    const float* dec         = (const float*)d_in[1];
    const int*   targets     = (const int*)d_in[2];
    const int*   inputs_len  = (const int*)d_in[3];
    const int*   targets_len = (const int*)d_in[4];
    const float* Wj          = (const float*)d_in[5];
    const float* bj          = (const float*)d_in[6];
    const float* Wo          = (const float*)d_in[7];
    const float* bo          = (const float*)d_in[8];
    float* out = (float*)d_out;

    char* ws = (char*)d_ws;
    float*          encp  = (float*)(ws + 0);                // 2400*512 f32 = 4,915,200
    float*          decp  = (float*)(ws + 4915200);          // 488*512 f32  =   999,424
    unsigned*       Z     = (unsigned*)(ws + 5914624);       // 8*384*64 half2 = 786,432
    unsigned short* WjT   = (unsigned short*)(ws + 6701056); // 512*320 bf16 =   327,680
    unsigned short* WoT2  = (unsigned short*)(ws + 7028736); // 128*512 bf16 =   131,072
    float*          bosum = (float*)(ws + 7159872);          // 128 f32

    hipMemsetAsync(bosum, 0, VOC * sizeof(float), stream);
    convert_w<<<224, 256, 0, stream>>>(Wj, Wo, WjT, WoT2, bosum);
    proj_mfma<<<184, 256, 0, stream>>>(enc, dec, WjT, bj, encp, decp);
    joint_mfma<<<1200, 512, 0, stream>>>(encp, decp, WoT2, bo, bosum, targets, (unsigned short*)Z);
    dp_kernel<<<1, 512, 0, stream>>>(Z, inputs_len, targets_len, out);
}